// Round 1
// baseline (142.956 us; speedup 1.0000x reference)
//
#include <hip/hip_runtime.h>

#define NQ   12
#define DIM  4096      // 2^NQ
#define NL   2
#define BATCH 4096

// ---------------------------------------------------------------------------
// Kernel 1: fuse the NL layers into 12 merged 2x2 complex gates.
// (A⊗B..)(C⊗D..) = (AC)⊗(BD)..  =>  G_q = U3(l=1,q) @ U3(l=0,q)
// Stored indexed by BIT position k = 11-q (qubit 0 = most significant bit).
// Layout: gates[k*8] = {r00,i00,r01,i01,r10,i10,r11,i11}
// ---------------------------------------------------------------------------
__global__ void build_gates(const float* __restrict__ th,
                            const float* __restrict__ ph,
                            const float* __restrict__ lm,
                            float* __restrict__ gates) {
    int q = threadIdx.x;
    if (q >= NQ) return;
    float g00r = 1.f, g00i = 0.f, g01r = 0.f, g01i = 0.f;
    float g10r = 0.f, g10i = 0.f, g11r = 1.f, g11i = 0.f;
    for (int l = 0; l < NL; ++l) {
        float th2 = 0.5f * th[l * NQ + q];
        float p   = ph[l * NQ + q];
        float la  = lm[l * NQ + q];
        float c = cosf(th2), s = sinf(th2);
        // U3 = [[c, -e^{i la} s], [e^{i p} s, e^{i(p+la)} c]]
        float u00r = c,                u00i = 0.f;
        float u01r = -cosf(la) * s,    u01i = -sinf(la) * s;
        float u10r = cosf(p) * s,      u10i = sinf(p) * s;
        float u11r = cosf(p + la) * c, u11i = sinf(p + la) * c;
        // G <- U * G
        float n00r = u00r*g00r - u00i*g00i + u01r*g10r - u01i*g10i;
        float n00i = u00r*g00i + u00i*g00r + u01r*g10i + u01i*g10r;
        float n01r = u00r*g01r - u00i*g01i + u01r*g11r - u01i*g11i;
        float n01i = u00r*g01i + u00i*g01r + u01r*g11i + u01i*g11r;
        float n10r = u10r*g00r - u10i*g00i + u11r*g10r - u11i*g10i;
        float n10i = u10r*g00i + u10i*g00r + u11r*g10i + u11i*g10r;
        float n11r = u10r*g01r - u10i*g01i + u11r*g11r - u11i*g11i;
        float n11i = u10r*g01i + u10i*g01r + u11r*g11i + u11i*g11r;
        g00r = n00r; g00i = n00i; g01r = n01r; g01i = n01i;
        g10r = n10r; g10i = n10i; g11r = n11r; g11i = n11i;
    }
    int k = (NQ - 1) - q;  // bit index (qubit 0 is MSB)
    float* o = gates + k * 8;
    o[0] = g00r; o[1] = g00i; o[2] = g01r; o[3] = g01i;
    o[4] = g10r; o[5] = g10i; o[6] = g11r; o[7] = g11i;
}

// ---------------------------------------------------------------------------
// Kernel 2: one block per sample. 256 threads x 16 complex elems in registers.
// 3 register stages (idx bits {0,1,10,11} / {2,3,4,5} / {6,7,8,9}), 2 LDS
// round-trips. Skewed split re/im LDS (off = idx + idx>>4) keeps all access
// patterns <=2-way bank aliasing. Normalization folded into epilogue.
// ---------------------------------------------------------------------------
struct Gate { float r00, i00, r01, i01, r10, i10, r11, i11; };

__device__ __forceinline__ Gate load_gate(const float* __restrict__ g, int k) {
    const float* p = g + k * 8;
    Gate q;
    q.r00 = p[0]; q.i00 = p[1]; q.r01 = p[2]; q.i01 = p[3];
    q.r10 = p[4]; q.i10 = p[5]; q.r11 = p[6]; q.i11 = p[7];
    return q;
}

__device__ __forceinline__ int lds_off(int idx) { return idx + (idx >> 4); }

__device__ __forceinline__ void apply_gate(float vr[16], float vi[16],
                                           int r0, int r1, const Gate& g) {
    float x0r = vr[r0], x0i = vi[r0], x1r = vr[r1], x1i = vi[r1];
    vr[r0] = g.r00 * x0r - g.i00 * x0i + g.r01 * x1r - g.i01 * x1i;
    vi[r0] = g.r00 * x0i + g.i00 * x0r + g.r01 * x1i + g.i01 * x1r;
    vr[r1] = g.r10 * x0r - g.i10 * x0i + g.r11 * x1r - g.i11 * x1i;
    vi[r1] = g.r10 * x0i + g.i10 * x0r + g.r11 * x1i + g.i11 * x1r;
}

// apply gate on register-bit rb (pairs differ in bit rb of the 4-bit reg idx)
__device__ __forceinline__ void apply_on_rbit(float vr[16], float vi[16],
                                              int rb, const Gate& g) {
    const int m = 1 << rb;
    #pragma unroll
    for (int h = 0; h < 8; ++h) {
        int low = h & (m - 1);
        int r   = ((h & ~(m - 1)) << 1) | low;   // insert 0 at bit rb
        apply_gate(vr, vi, r, r | m, g);
    }
}

__global__ __launch_bounds__(256, 4)
void qc_sim(const float* __restrict__ in, const float* __restrict__ gates,
            float* __restrict__ out) {
    __shared__ float sre[DIM + DIM / 16];
    __shared__ float simg[DIM + DIM / 16];
    __shared__ float red[4];

    const int t = threadIdx.x;
    const int b = blockIdx.x;

    float vr[16], vi[16];
    float ss = 0.f;

    // ---- load (coalesced float4): idx = j*1024 + t*4 + e, reg r = j*4+e ----
    const float4* __restrict__ x4 =
        reinterpret_cast<const float4*>(in + (size_t)b * DIM);
    #pragma unroll
    for (int j = 0; j < 4; ++j) {
        float4 v = x4[j * 256 + t];
        int r = j * 4;
        vr[r] = v.x; vr[r + 1] = v.y; vr[r + 2] = v.z; vr[r + 3] = v.w;
        ss += v.x * v.x + v.y * v.y + v.z * v.z + v.w * v.w;
    }
    // wave-level sum of squares -> per-wave slot in LDS
    #pragma unroll
    for (int off = 32; off > 0; off >>= 1)
        ss += __shfl_down(ss, off, 64);
    if ((t & 63) == 0) red[t >> 6] = ss;

    // ---- stage 1: gates on idx bits 0,1 (reg bits 0,1) and 10,11 (2,3) ----
    {
        Gate g0 = load_gate(gates, 0);
        // first gate: imaginary inputs are exactly zero -> specialized
        #pragma unroll
        for (int r = 0; r < 16; r += 2) {
            float x0 = vr[r], x1 = vr[r + 1];
            vr[r]     = g0.r00 * x0 + g0.r01 * x1;
            vi[r]     = g0.i00 * x0 + g0.i01 * x1;
            vr[r + 1] = g0.r10 * x0 + g0.r11 * x1;
            vi[r + 1] = g0.i10 * x0 + g0.i11 * x1;
        }
        Gate g1 = load_gate(gates, 1);
        apply_on_rbit(vr, vi, 1, g1);
        Gate ga = load_gate(gates, 10);
        apply_on_rbit(vr, vi, 2, ga);
        Gate gb = load_gate(gates, 11);
        apply_on_rbit(vr, vi, 3, gb);
    }
    #pragma unroll
    for (int r = 0; r < 16; ++r) {
        int idx = ((r >> 2) << 10) + t * 4 + (r & 3);
        int o = lds_off(idx);
        sre[o] = vr[r]; simg[o] = vi[r];
    }
    __syncthreads();

    // ---- stage 2: idx = (t>>2)<<6 | r<<2 | t&3 ; gates on bits 2..5 ----
    #pragma unroll
    for (int r = 0; r < 16; ++r) {
        int idx = ((t >> 2) << 6) + (r << 2) + (t & 3);
        int o = lds_off(idx);
        vr[r] = sre[o]; vi[r] = simg[o];
    }
    {
        Gate g2 = load_gate(gates, 2);
        apply_on_rbit(vr, vi, 0, g2);
        Gate g3 = load_gate(gates, 3);
        apply_on_rbit(vr, vi, 1, g3);
        Gate g4 = load_gate(gates, 4);
        apply_on_rbit(vr, vi, 2, g4);
        Gate g5 = load_gate(gates, 5);
        apply_on_rbit(vr, vi, 3, g5);
    }
    #pragma unroll
    for (int r = 0; r < 16; ++r) {
        int idx = ((t >> 2) << 6) + (r << 2) + (t & 3);
        int o = lds_off(idx);
        sre[o] = vr[r]; simg[o] = vi[r];
    }
    __syncthreads();

    // ---- stage 3: idx = (t>>6)<<10 | r<<6 | t&63 ; gates on bits 6..9 ----
    #pragma unroll
    for (int r = 0; r < 16; ++r) {
        int idx = ((t >> 6) << 10) + (r << 6) + (t & 63);
        int o = lds_off(idx);
        vr[r] = sre[o]; vi[r] = simg[o];
    }
    {
        Gate g6 = load_gate(gates, 6);
        apply_on_rbit(vr, vi, 0, g6);
        Gate g7 = load_gate(gates, 7);
        apply_on_rbit(vr, vi, 1, g7);
        Gate g8 = load_gate(gates, 8);
        apply_on_rbit(vr, vi, 2, g8);
        Gate g9 = load_gate(gates, 9);
        apply_on_rbit(vr, vi, 3, g9);
    }

    // ---- epilogue: prob = |state|^2 / ||x||^2, coalesced b32 stores ----
    float tot = red[0] + red[1] + red[2] + red[3];
    float inv = 1.0f / tot;
    float* __restrict__ o = out + (size_t)b * DIM;
    #pragma unroll
    for (int r = 0; r < 16; ++r) {
        int idx = ((t >> 6) << 10) + (r << 6) + (t & 63);
        o[idx] = (vr[r] * vr[r] + vi[r] * vi[r]) * inv;
    }
}

extern "C" void kernel_launch(void* const* d_in, const int* in_sizes, int n_in,
                              void* d_out, int out_size, void* d_ws, size_t ws_size,
                              hipStream_t stream) {
    (void)in_sizes; (void)n_in; (void)out_size; (void)ws_size;
    const float* inputs = (const float*)d_in[0];
    const float* thetas = (const float*)d_in[1];
    const float* phis   = (const float*)d_in[2];
    const float* lams   = (const float*)d_in[3];
    float* gates = (float*)d_ws;              // 96 floats of scratch
    float* out   = (float*)d_out;

    hipLaunchKernelGGL(build_gates, dim3(1), dim3(64), 0, stream,
                       thetas, phis, lams, gates);
    hipLaunchKernelGGL(qc_sim, dim3(BATCH), dim3(256), 0, stream,
                       inputs, gates, out);
}

// Round 2
// 137.401 us; speedup vs baseline: 1.0404x; 1.0404x over previous
//
#include <hip/hip_runtime.h>

#define NQ   12
#define DIM  4096      // 2^NQ
#define NL   2
#define BATCH 4096

typedef float v2f __attribute__((ext_vector_type(2)));

// ---------------------------------------------------------------------------
// One kernel. Per block: 12 lanes build the layer-fused gates into LDS
// ((A⊗B..)(C⊗D..) = (AC)⊗(BD)..), then 256 threads x 16 complex elems apply
// 12 butterflies in 3 register stages with 2 LDS transposes.
// Complex state kept as <2 x float> (re,im) so gate math compiles to
// v_pk_fma_f32 and LDS transposes use ds_{read,write}_b64.
// Skew off = idx + (idx>>4) puts every transpose pattern at the LDS BW floor.
// ---------------------------------------------------------------------------

struct PGate { v2f a00, b00, a01, b01, a10, b10, a11, b11; };

__device__ __forceinline__ PGate make_pg(const float* __restrict__ g) {
    PGate p;
    float r00 = g[0], i00 = g[1], r01 = g[2], i01 = g[3];
    float r10 = g[4], i10 = g[5], r11 = g[6], i11 = g[7];
    p.a00 = (v2f){ r00, i00 };  p.b00 = (v2f){ -i00, r00 };
    p.a01 = (v2f){ r01, i01 };  p.b01 = (v2f){ -i01, r01 };
    p.a10 = (v2f){ r10, i10 };  p.b10 = (v2f){ -i10, r10 };
    p.a11 = (v2f){ r11, i11 };  p.b11 = (v2f){ -i11, r11 };
    return p;
}

// y0 = g00*x0 + g01*x1 ; y1 = g10*x0 + g11*x1  (complex, packed re/im)
__device__ __forceinline__ void papply(v2f v[16], int r0, int r1, const PGate& g) {
    v2f x0 = v[r0], x1 = v[r1];
    v2f x0r = (v2f){ x0.x, x0.x }, x0i = (v2f){ x0.y, x0.y };
    v2f x1r = (v2f){ x1.x, x1.x }, x1i = (v2f){ x1.y, x1.y };
    v[r0] = g.a00 * x0r + g.b00 * x0i + g.a01 * x1r + g.b01 * x1i;
    v[r1] = g.a10 * x0r + g.b10 * x0i + g.a11 * x1r + g.b11 * x1i;
}

// apply gate on register-bit rb (pairs differ in bit rb of the 4-bit reg idx)
__device__ __forceinline__ void papply_rbit(v2f v[16], int rb, const PGate& g) {
    const int m = 1 << rb;
    #pragma unroll
    for (int h = 0; h < 8; ++h) {
        int low = h & (m - 1);
        int r   = ((h & ~(m - 1)) << 1) | low;   // insert 0 at bit rb
        papply(v, r, r | m, g);
    }
}

__device__ __forceinline__ int lds_off(int idx) { return idx + (idx >> 4); }

__global__ __launch_bounds__(256, 4)
void qc_sim(const float* __restrict__ in,
            const float* __restrict__ th,
            const float* __restrict__ ph,
            const float* __restrict__ lm,
            float* __restrict__ out) {
    __shared__ v2f   st[DIM + DIM / 16];   // skewed complex state
    __shared__ float sg[NQ][8];            // fused gates, indexed by bit k
    __shared__ float red[4];

    const int t = threadIdx.x;
    const int b = blockIdx.x;

    v2f v[16];
    float ss = 0.f;

    // ---- issue global loads first (coalesced float4); overlap gate build ----
    const float4* __restrict__ x4 =
        reinterpret_cast<const float4*>(in + (size_t)b * DIM);
    #pragma unroll
    for (int j = 0; j < 4; ++j) {
        float4 w = x4[j * 256 + t];
        int r = j * 4;
        v[r]     = (v2f){ w.x, 0.f };
        v[r + 1] = (v2f){ w.y, 0.f };
        v[r + 2] = (v2f){ w.z, 0.f };
        v[r + 3] = (v2f){ w.w, 0.f };
        ss += w.x * w.x + w.y * w.y + w.z * w.z + w.w * w.w;
    }
    #pragma unroll
    for (int off = 32; off > 0; off >>= 1)
        ss += __shfl_down(ss, off, 64);
    if ((t & 63) == 0) red[t >> 6] = ss;

    // ---- 12 lanes build the layer-fused 2x2 gates ----
    if (t < NQ) {
        int q = t;
        float g00r = 1.f, g00i = 0.f, g01r = 0.f, g01i = 0.f;
        float g10r = 0.f, g10i = 0.f, g11r = 1.f, g11i = 0.f;
        #pragma unroll
        for (int l = 0; l < NL; ++l) {
            float th2 = 0.5f * th[l * NQ + q];
            float p   = ph[l * NQ + q];
            float la  = lm[l * NQ + q];
            float c = cosf(th2), s = sinf(th2);
            float u00r = c,                u00i = 0.f;
            float u01r = -cosf(la) * s,    u01i = -sinf(la) * s;
            float u10r = cosf(p) * s,      u10i = sinf(p) * s;
            float u11r = cosf(p + la) * c, u11i = sinf(p + la) * c;
            float n00r = u00r*g00r - u00i*g00i + u01r*g10r - u01i*g10i;
            float n00i = u00r*g00i + u00i*g00r + u01r*g10i + u01i*g10r;
            float n01r = u00r*g01r - u00i*g01i + u01r*g11r - u01i*g11i;
            float n01i = u00r*g01i + u00i*g01r + u01r*g11i + u01i*g11r;
            float n10r = u10r*g00r - u10i*g00i + u11r*g10r - u11i*g10i;
            float n10i = u10r*g00i + u10i*g00r + u11r*g10i + u11i*g10r;
            float n11r = u10r*g01r - u10i*g01i + u11r*g11r - u11i*g11i;
            float n11i = u10r*g01i + u10i*g01r + u11r*g11i + u11i*g11r;
            g00r = n00r; g00i = n00i; g01r = n01r; g01i = n01i;
            g10r = n10r; g10i = n10i; g11r = n11r; g11i = n11i;
        }
        int k = (NQ - 1) - q;  // qubit 0 is the MSB of the state index
        sg[k][0] = g00r; sg[k][1] = g00i; sg[k][2] = g01r; sg[k][3] = g01i;
        sg[k][4] = g10r; sg[k][5] = g10i; sg[k][6] = g11r; sg[k][7] = g11i;
    }
    __syncthreads();

    // ---- stage 1: regs = idx bits {0,1,10,11}; gates 0,1,10,11 ----
    {
        PGate g0 = make_pg(sg[0]);
        // first gate: imaginary inputs exactly zero -> 4 pk-ops per pair
        #pragma unroll
        for (int r = 0; r < 16; r += 2) {
            v2f x0r = (v2f){ v[r].x,     v[r].x     };
            v2f x1r = (v2f){ v[r + 1].x, v[r + 1].x };
            v[r]     = g0.a00 * x0r + g0.a01 * x1r;
            v[r + 1] = g0.a10 * x0r + g0.a11 * x1r;
        }
        { PGate g = make_pg(sg[1]);  papply_rbit(v, 1, g); }
        { PGate g = make_pg(sg[10]); papply_rbit(v, 2, g); }
        { PGate g = make_pg(sg[11]); papply_rbit(v, 3, g); }
    }
    #pragma unroll
    for (int r = 0; r < 16; ++r) {
        int idx = ((r >> 2) << 10) + t * 4 + (r & 3);
        st[lds_off(idx)] = v[r];
    }
    __syncthreads();

    // ---- stage 2: regs = idx bits {2,3,4,5}; gates 2..5 ----
    #pragma unroll
    for (int r = 0; r < 16; ++r) {
        int idx = ((t >> 2) << 6) + (r << 2) + (t & 3);
        v[r] = st[lds_off(idx)];
    }
    { PGate g = make_pg(sg[2]); papply_rbit(v, 0, g); }
    { PGate g = make_pg(sg[3]); papply_rbit(v, 1, g); }
    { PGate g = make_pg(sg[4]); papply_rbit(v, 2, g); }
    { PGate g = make_pg(sg[5]); papply_rbit(v, 3, g); }
    __syncthreads();
    #pragma unroll
    for (int r = 0; r < 16; ++r) {
        int idx = ((t >> 2) << 6) + (r << 2) + (t & 3);
        st[lds_off(idx)] = v[r];
    }
    __syncthreads();

    // ---- stage 3: regs = idx bits {6,7,8,9}; gates 6..9 ----
    #pragma unroll
    for (int r = 0; r < 16; ++r) {
        int idx = ((t >> 6) << 10) + (r << 6) + (t & 63);
        v[r] = st[lds_off(idx)];
    }
    { PGate g = make_pg(sg[6]); papply_rbit(v, 0, g); }
    { PGate g = make_pg(sg[7]); papply_rbit(v, 1, g); }
    { PGate g = make_pg(sg[8]); papply_rbit(v, 2, g); }
    { PGate g = make_pg(sg[9]); papply_rbit(v, 3, g); }

    // ---- epilogue: prob = |state|^2 / ||x||^2, coalesced stores ----
    float tot = red[0] + red[1] + red[2] + red[3];
    float inv = 1.0f / tot;
    float* __restrict__ o = out + (size_t)b * DIM;
    #pragma unroll
    for (int r = 0; r < 16; ++r) {
        int idx = ((t >> 6) << 10) + (r << 6) + (t & 63);
        v2f p2 = v[r] * v[r];
        o[idx] = (p2.x + p2.y) * inv;
    }
}

extern "C" void kernel_launch(void* const* d_in, const int* in_sizes, int n_in,
                              void* d_out, int out_size, void* d_ws, size_t ws_size,
                              hipStream_t stream) {
    (void)in_sizes; (void)n_in; (void)out_size; (void)d_ws; (void)ws_size;
    const float* inputs = (const float*)d_in[0];
    const float* thetas = (const float*)d_in[1];
    const float* phis   = (const float*)d_in[2];
    const float* lams   = (const float*)d_in[3];
    float* out = (float*)d_out;

    hipLaunchKernelGGL(qc_sim, dim3(BATCH), dim3(256), 0, stream,
                       inputs, thetas, phis, lams, out);
}